// Round 10
// baseline (227.273 us; speedup 1.0000x reference)
//
#include <hip/hip_runtime.h>

typedef __bf16 bf16;
typedef __bf16 bf16x4 __attribute__((ext_vector_type(4)));
typedef __bf16 bf16x8 __attribute__((ext_vector_type(8)));
typedef short  s16x4  __attribute__((ext_vector_type(4)));
typedef float  f32x4  __attribute__((ext_vector_type(4)));

#define VOC 65

// workspace layout (element offsets, bf16)
#define WS_WQ 0
#define WS_WK 16384
#define WS_WV 32768
#define WS_WO 49152
#define WS_W1 65536
#define WS_W2 196608
#define WS_WF 327680   // padded [80][32]

// ---------------- prep kernels: f32 -> bf16 transpose to [col][k] (k contiguous) ----------------
__global__ void transpose_f32bf16_k(const float* __restrict__ src, bf16* __restrict__ dst,
                                    int batch, int R, int C) {
  int i = blockIdx.x * blockDim.x + threadIdx.x;
  int total = batch * R * C;
  if (i >= total) return;
  int b = i / (R * C);
  int rc = i - b * (R * C);
  int r = rc / C;
  int c = rc - r * C;
  dst[(b * C + c) * R + r] = (bf16)src[i];   // [b][R][C] -> [b][C][R]
}

__global__ void prep_wf_k(const float* __restrict__ wf, bf16* __restrict__ dst) {
  int i = blockIdx.x * blockDim.x + threadIdx.x;  // 80*32
  if (i >= 80 * 32) return;
  int c = i >> 5, r = i & 31;
  dst[i] = (c < VOC) ? (bf16)wf[r * VOC + c] : (bf16)0.0f;  // [80 cols][32 k], cols 65..79 zero
}

// ---------------- fused transformer: register MFMA chaining + wave-pair split ----------------
// Pair (2 waves) owns 2 seqs; waves split heads {0,1}|{2,3} and FFN hid halves.
// Partial accumulators summed via LDS f32x4 exchange. 4096 waves total (4/SIMD).

#define MFMA32(a,b,c) __builtin_amdgcn_mfma_f32_16x16x32_bf16((a),(b),(c),0,0,0)

static __device__ __forceinline__ f32x4 MFMA16(bf16x4 a, bf16x4 b, f32x4 c) {
  return __builtin_amdgcn_mfma_f32_16x16x16bf16_1k(
      __builtin_bit_cast(s16x4, a), __builtin_bit_cast(s16x4, b), c, 0, 0, 0);
}

__global__ __launch_bounds__(256)
void xformer_k(const int* __restrict__ x, const float* __restrict__ emb, const float* __restrict__ pos,
               const float* __restrict__ bq, const float* __restrict__ bk, const float* __restrict__ bv,
               const float* __restrict__ bo, const float* __restrict__ ga, const float* __restrict__ ba,
               const float* __restrict__ b1, const float* __restrict__ b2,
               const float* __restrict__ gm, const float* __restrict__ bm,
               const float* __restrict__ bfin,
               const bf16* __restrict__ ws, float* __restrict__ out)
{
  __shared__ f32x4 redA[2][2][2][2][64];   // [pair][sub][si][n2][lane] partial acc, 16 KB
  __shared__ bf16  hbounce[2][2][16][40];  // [pair][si][tok][dim] LN transpose bounce, 5 KB
  const int tid  = threadIdx.x;
  const int wv   = tid >> 6;
  const int pairId = wv >> 1;
  const int sub  = wv & 1;                 // head/hid split within pair
  const int lane = tid & 63;
  const int lo   = lane & 15;
  const int hi   = lane >> 4;              // 0..3
  const int seq0 = blockIdx.x * 4 + pairId * 2;

  const bf16* wqT = ws + WS_WQ;            // [l*4+h][64 out][32 k]
  const bf16* wkT = ws + WS_WK;
  const bf16* wvT = ws + WS_WV;
  const bf16* woT = ws + WS_WO;            // [l][32 out][256 k]
  const bf16* w1T = ws + WS_W1;            // [l][2048 hid][32 k]
  const bf16* w2T = ws + WS_W2;            // [l][32 out][2048 k]
  const bf16* wfT = ws + WS_WF;            // [80 voc][32 k]

  const f32x4 fz = {0.f, 0.f, 0.f, 0.f};

  // Register state per seq: bh = h A/B-frag [tok=lo][dim=hi*8+j];
  // hD0/hD1 = h D-layout [tok=4hi+r][dim=lo / 16+lo] (residual copy)
  bf16x8 bh[2];
  bf16x4 hD0[2], hD1[2];

  // ---- embedding: h = (emb[x] + pos) * sqrt(32), straight to registers ----
  #pragma unroll
  for (int si = 0; si < 2; ++si) {
    const int s = seq0 + si;
    int idl = x[s*16 + lo];
    idl = idl < 0 ? 0 : (idl >= VOC ? VOC - 1 : idl);
    f32x4 e0 = *(const f32x4*)(emb + idl*32 + hi*8);
    f32x4 e1 = *(const f32x4*)(emb + idl*32 + hi*8 + 4);
    f32x4 p0 = *(const f32x4*)(pos + lo*32 + hi*8);
    f32x4 p1 = *(const f32x4*)(pos + lo*32 + hi*8 + 4);
    bf16x8 hv;
    #pragma unroll
    for (int j = 0; j < 4; ++j) {
      hv[j]   = (bf16)((e0[j] + p0[j]) * 5.656854249492381f);
      hv[4+j] = (bf16)((e1[j] + p1[j]) * 5.656854249492381f);
    }
    bh[si] = hv;
    bf16x4 d0, d1;
    #pragma unroll
    for (int r = 0; r < 4; ++r) {
      int tr = hi*4 + r;
      int idr = x[s*16 + tr];
      idr = idr < 0 ? 0 : (idr >= VOC ? VOC - 1 : idr);
      d0[r] = (bf16)((emb[idr*32 + lo]      + pos[tr*32 + lo])      * 5.656854249492381f);
      d1[r] = (bf16)((emb[idr*32 + 16 + lo] + pos[tr*32 + 16 + lo]) * 5.656854249492381f);
    }
    hD0[si] = d0; hD1[si] = d1;
  }

  #pragma unroll
  for (int l = 0; l < 2; ++l) {
    // ================= attention: this wave does heads {2 sub, 2 sub+1} =================
    f32x4 accO[2][2] = {{fz,fz},{fz,fz}};  // partial D: [tok=4hi+r][out=n2*16+lo]
    #pragma unroll
    for (int hhl = 0; hhl < 2; ++hhl) {
      const int hh = sub*2 + hhl;
      const int hb = (l*4 + hh) * 64;
      // ---- Q,K proj (swapped MFMA32) fused into scores (MFMA16 chain) ----
      f32x4 sf[2] = {fz, fz};
      #pragma unroll
      for (int nt = 0; nt < 4; ++nt) {
        const int wofs = (hb + nt*16 + lo)*32 + hi*8;
        bf16x8 wq8 = *(const bf16x8*)(wqT + wofs);
        bf16x8 wk8 = *(const bf16x8*)(wkT + wofs);
        f32x4 bq4 = *(const f32x4*)(bq + hb + nt*16 + hi*4);
        f32x4 bk4 = *(const f32x4*)(bk + hb + nt*16 + hi*4);
        #pragma unroll
        for (int si = 0; si < 2; ++si) {
          f32x4 dq = MFMA32(wq8, bh[si], fz);   // Q[out=nt16+4hi+r][tok=lo]
          f32x4 dk = MFMA32(wk8, bh[si], fz);
          bf16x4 pq, pk;
          #pragma unroll
          for (int r = 0; r < 4; ++r) {
            pq[r] = (bf16)(dq[r] + bq4[r]);
            pk[r] = (bf16)(dk[r] + bk4[r]);
          }
          sf[si] = MFMA16(pk, pq, sf[si]);      // S[key=4hi+r][query=lo]
        }
      }
      // ---- softmax (in-register) ----
      bf16x4 pp[2];
      #pragma unroll
      for (int si = 0; si < 2; ++si) {
        float e[4], mx = -3.0e4f, sm = 0.f;
        #pragma unroll
        for (int r = 0; r < 4; ++r) {
          int key = hi*4 + r;
          e[r] = (key <= lo) ? sf[si][r] * 0.125f : -3.0e4f;
          mx = fmaxf(mx, e[r]);
        }
        mx = fmaxf(mx, __shfl_xor(mx, 16));
        mx = fmaxf(mx, __shfl_xor(mx, 32));
        #pragma unroll
        for (int r = 0; r < 4; ++r) { e[r] = __expf(e[r] - mx); sm += e[r]; }
        sm += __shfl_xor(sm, 16);
        sm += __shfl_xor(sm, 32);
        float inv = 1.0f / sm;
        bf16x4 p4;
        #pragma unroll
        for (int r = 0; r < 4; ++r) p4[r] = (bf16)(e[r] * inv);
        pp[si] = p4;                            // B-frag [col=query=lo][k=key 4hi+j]
      }
      // ---- V proj + PV + out-proj (register-chained) ----
      #pragma unroll
      for (int nt = 0; nt < 4; ++nt) {
        bf16x8 wv8 = *(const bf16x8*)(wvT + (hb + nt*16 + lo)*32 + hi*8);
        float bvv = bv[hb + nt*16 + lo];
        bf16x4 wo4[2];
        #pragma unroll
        for (int n2 = 0; n2 < 2; ++n2)
          wo4[n2] = *(const bf16x4*)(woT + (l*32 + n2*16 + lo)*256 + hh*64 + nt*16 + hi*4);
        #pragma unroll
        for (int si = 0; si < 2; ++si) {
          f32x4 dv = MFMA32(bh[si], wv8, fz);   // V[tok=4hi+r][vdim=nt16+lo]
          bf16x4 vz;
          #pragma unroll
          for (int r = 0; r < 4; ++r) vz[r] = (bf16)(dv[r] + bvv);
          f32x4 o = MFMA16(vz, pp[si], fz);     // O[vdim=nt16+4hi+r][tok=lo]
          bf16x4 oz;
          #pragma unroll
          for (int r = 0; r < 4; ++r) oz[r] = (bf16)o[r];
          #pragma unroll
          for (int n2 = 0; n2 < 2; ++n2)
            accO[si][n2] = MFMA16(oz, wo4[n2], accO[si][n2]);  // [tok=4hi+r][out=n2*16+lo]
        }
      }
    }
    // ---- pair-sum partial accO ----
    #pragma unroll
    for (int si = 0; si < 2; ++si)
      #pragma unroll
      for (int n2 = 0; n2 < 2; ++n2)
        redA[pairId][sub][si][n2][lane] = accO[si][n2];
    __syncthreads();
    #pragma unroll
    for (int si = 0; si < 2; ++si)
      #pragma unroll
      for (int n2 = 0; n2 < 2; ++n2)
        accO[si][n2] += redA[pairId][sub^1][si][n2][lane];
    // ---- + bo + residual + LN(ga,ba) (both waves, identical); rebuild bh ----
    {
      float o0 = bo[l*32 + lo], o1 = bo[l*32 + 16 + lo];
      float g0 = ga[l*32 + lo], g1 = ga[l*32 + 16 + lo];
      float a0 = ba[l*32 + lo], a1 = ba[l*32 + 16 + lo];
      #pragma unroll
      for (int si = 0; si < 2; ++si) {
        bf16x4 nh0, nh1;
        #pragma unroll
        for (int r = 0; r < 4; ++r) {
          float v0 = accO[si][0][r] + o0 + (float)hD0[si][r];
          float v1 = accO[si][1][r] + o1 + (float)hD1[si][r];
          float s1 = v0 + v1, s2 = v0*v0 + v1*v1;
          s1 += __shfl_xor(s1, 1); s2 += __shfl_xor(s2, 1);
          s1 += __shfl_xor(s1, 2); s2 += __shfl_xor(s2, 2);
          s1 += __shfl_xor(s1, 4); s2 += __shfl_xor(s2, 4);
          s1 += __shfl_xor(s1, 8); s2 += __shfl_xor(s2, 8);
          float mean = s1 * (1.f/32.f);
          float var  = s2 * (1.f/32.f) - mean*mean;
          float rs   = rsqrtf(fabsf(var) + 1e-5f);
          float h0 = (v0 - mean)*rs*g0 + a0;
          float h1 = (v1 - mean)*rs*g1 + a1;
          nh0[r] = (bf16)h0; nh1[r] = (bf16)h1;
          if (sub == 0) {
            hbounce[pairId][si][hi*4 + r][lo]      = (bf16)h0;
            hbounce[pairId][si][hi*4 + r][16 + lo] = (bf16)h1;
          }
        }
        hD0[si] = nh0; hD1[si] = nh1;
      }
      __syncthreads();
      #pragma unroll
      for (int si = 0; si < 2; ++si)
        bh[si] = *(const bf16x8*)(&hbounce[pairId][si][lo][hi*8]);
    }
    // ================= FFN: this wave does hid [sub*1024, sub*1024+1024) =================
    f32x4 acc2[2][2] = {{fz,fz},{fz,fz}};  // partial D: [tok=4hi+r][out=n2*16+lo]
    const bf16* w1l = w1T + l*65536;
    const bf16* w2l = w2T + l*65536;
    const float* b1l = b1 + l*2048;
    const int hbase = sub * 1024;
    // preload step 0
    bf16x8 w1c  = *(const bf16x8*)(w1l + (hbase + lo)*32 + hi*8);
    f32x4  b1c  = *(const f32x4*)(b1l + hbase + hi*4);
    bf16x4 w2c0 = *(const bf16x4*)(w2l + (lo)*2048      + hbase + hi*4);
    bf16x4 w2c1 = *(const bf16x4*)(w2l + (16 + lo)*2048 + hbase + hi*4);
    for (int t = 0; t < 64; ++t) {
      // prefetch step t+1 (wraps at t=63; unused)
      const int hidn = hbase + ((t + 1) & 63) * 16;
      bf16x8 w1n  = *(const bf16x8*)(w1l + (hidn + lo)*32 + hi*8);
      f32x4  b1n  = *(const f32x4*)(b1l + hidn + hi*4);
      bf16x4 w2n0 = *(const bf16x4*)(w2l + (lo)*2048      + hidn + hi*4);
      bf16x4 w2n1 = *(const bf16x4*)(w2l + (16 + lo)*2048 + hidn + hi*4);
      #pragma unroll
      for (int si = 0; si < 2; ++si) {
        f32x4 dm = MFMA32(w1c, bh[si], fz);     // m[hid=hidb+4hi+r][tok=lo]
        bf16x4 mz;
        #pragma unroll
        for (int r = 0; r < 4; ++r) mz[r] = (bf16)fmaxf(dm[r] + b1c[r], 0.f);
        acc2[si][0] = MFMA16(mz, w2c0, acc2[si][0]);
        acc2[si][1] = MFMA16(mz, w2c1, acc2[si][1]);
      }
      w1c = w1n; b1c = b1n; w2c0 = w2n0; w2c1 = w2n1;
    }
    // ---- pair-sum partial acc2 ----
    #pragma unroll
    for (int si = 0; si < 2; ++si)
      #pragma unroll
      for (int n2 = 0; n2 < 2; ++n2)
        redA[pairId][sub][si][n2][lane] = acc2[si][n2];
    __syncthreads();
    #pragma unroll
    for (int si = 0; si < 2; ++si)
      #pragma unroll
      for (int n2 = 0; n2 < 2; ++n2)
        acc2[si][n2] += redA[pairId][sub^1][si][n2][lane];
    // ---- + b2 + residual + LN(gm,bm); rebuild bh ----
    {
      float c0 = b2[l*32 + lo], c1 = b2[l*32 + 16 + lo];
      float g0 = gm[l*32 + lo], g1 = gm[l*32 + 16 + lo];
      float a0 = bm[l*32 + lo], a1 = bm[l*32 + 16 + lo];
      #pragma unroll
      for (int si = 0; si < 2; ++si) {
        bf16x4 nh0, nh1;
        #pragma unroll
        for (int r = 0; r < 4; ++r) {
          float v0 = acc2[si][0][r] + c0 + (float)hD0[si][r];
          float v1 = acc2[si][1][r] + c1 + (float)hD1[si][r];
          float s1 = v0 + v1, s2 = v0*v0 + v1*v1;
          s1 += __shfl_xor(s1, 1); s2 += __shfl_xor(s2, 1);
          s1 += __shfl_xor(s1, 2); s2 += __shfl_xor(s2, 2);
          s1 += __shfl_xor(s1, 4); s2 += __shfl_xor(s2, 4);
          s1 += __shfl_xor(s1, 8); s2 += __shfl_xor(s2, 8);
          float mean = s1 * (1.f/32.f);
          float var  = s2 * (1.f/32.f) - mean*mean;
          float rs   = rsqrtf(fabsf(var) + 1e-5f);
          float h0 = (v0 - mean)*rs*g0 + a0;
          float h1 = (v1 - mean)*rs*g1 + a1;
          nh0[r] = (bf16)h0; nh1[r] = (bf16)h1;
          if (sub == 0) {
            hbounce[pairId][si][hi*4 + r][lo]      = (bf16)h0;
            hbounce[pairId][si][hi*4 + r][16 + lo] = (bf16)h1;
          }
        }
        hD0[si] = nh0; hD1[si] = nh1;
      }
      __syncthreads();
      #pragma unroll
      for (int si = 0; si < 2; ++si)
        bh[si] = *(const bf16x8*)(&hbounce[pairId][si][lo][hi*8]);
    }
  }

  // ---- final classifier: h @ Wf + bf; pair splits voc chunks (sub0: 0-2, sub1: 3-4) ----
  #pragma unroll
  for (int si = 0; si < 2; ++si) {
    const int s = seq0 + si;
    bf16x8 a = bh[si];
    for (int nt = sub ? 3 : 0; nt < (sub ? 5 : 3); ++nt) {
      bf16x8 w = *(const bf16x8*)(wfT + (nt*16 + lo)*32 + hi*8);
      f32x4 d = MFMA32(a, w, fz);              // D[tok=4hi+r][voc=nt16+lo]
      int col = nt*16 + lo;
      if (col < VOC) {
        float bb = bfin[col];
        #pragma unroll
        for (int r = 0; r < 4; ++r)
          out[(s*16 + hi*4 + r)*VOC + col] = d[r] + bb;
      }
    }
  }
}

extern "C" void kernel_launch(void* const* d_in, const int* in_sizes, int n_in,
                              void* d_out, int out_size, void* d_ws, size_t ws_size,
                              hipStream_t stream) {
  const int*   x   = (const int*)d_in[0];
  const float* emb = (const float*)d_in[1];
  const float* pos = (const float*)d_in[2];
  const float* Wq  = (const float*)d_in[3];
  const float* bq  = (const float*)d_in[4];
  const float* Wk  = (const float*)d_in[5];
  const float* bk  = (const float*)d_in[6];
  const float* Wv  = (const float*)d_in[7];
  const float* bv  = (const float*)d_in[8];
  const float* Wo  = (const float*)d_in[9];
  const float* bo  = (const float*)d_in[10];
  const float* ga  = (const float*)d_in[11];
  const float* ba  = (const float*)d_in[12];
  const float* W1  = (const float*)d_in[13];
  const float* b1  = (const float*)d_in[14];
  const float* W2  = (const float*)d_in[15];
  const float* b2  = (const float*)d_in[16];
  const float* gm  = (const float*)d_in[17];
  const float* bm  = (const float*)d_in[18];
  const float* Wf  = (const float*)d_in[19];
  const float* bfin= (const float*)d_in[20];

  bf16* ws = (bf16*)d_ws;

  // transpose weights (f32 -> bf16) into MFMA [out][k] layout (k contiguous)
  transpose_f32bf16_k<<<64, 256, 0, stream>>>(Wq, ws + WS_WQ, 8, 32, 64);
  transpose_f32bf16_k<<<64, 256, 0, stream>>>(Wk, ws + WS_WK, 8, 32, 64);
  transpose_f32bf16_k<<<64, 256, 0, stream>>>(Wv, ws + WS_WV, 8, 32, 64);
  transpose_f32bf16_k<<<64, 256, 0, stream>>>(Wo, ws + WS_WO, 2, 256, 32);
  transpose_f32bf16_k<<<512, 256, 0, stream>>>(W1, ws + WS_W1, 2, 32, 2048);
  transpose_f32bf16_k<<<512, 256, 0, stream>>>(W2, ws + WS_W2, 2, 2048, 32);
  prep_wf_k<<<10, 256, 0, stream>>>(Wf, ws + WS_WF);

  // fused transformer: 1024 blocks x 256 threads (2 wave-pairs x 2 seqs), 4096 waves
  xformer_k<<<1024, 256, 0, stream>>>(x, emb, pos, bq, bk, bv, bo, ga, ba,
                                      b1, b2, gm, bm, bfin,
                                      ws, (float*)d_out);
}

// Round 11
// 169.043 us; speedup vs baseline: 1.3445x; 1.3445x over previous
//
#include <hip/hip_runtime.h>

typedef __bf16 bf16;
typedef __bf16 bf16x4 __attribute__((ext_vector_type(4)));
typedef __bf16 bf16x8 __attribute__((ext_vector_type(8)));
typedef float  f32x4  __attribute__((ext_vector_type(4)));

#define VOC 65

// Intra-wave LDS produce->consume fence: compiler memory barrier + DS drain.
// Does NOT drain vmcnt (weight prefetch stays in flight), no cross-wave sync.
// Valid because every LDS buffer is wave-private and same-wave DS ops are
// processed in order by the DS pipe.
#define LDS_FENCE() asm volatile("s_waitcnt lgkmcnt(0)" ::: "memory")

// workspace layout (element offsets, bf16)
#define WS_WQ 0
#define WS_WK 16384
#define WS_WV 32768
#define WS_WO 49152
#define WS_W1 65536
#define WS_W2 196608
#define WS_WF 327680   // padded [80][32]

// ---------------- prep kernels: f32 -> bf16 transpose to [col][k] (k contiguous) ----------------
__global__ void transpose_f32bf16_k(const float* __restrict__ src, bf16* __restrict__ dst,
                                    int batch, int R, int C) {
  int i = blockIdx.x * blockDim.x + threadIdx.x;
  int total = batch * R * C;
  if (i >= total) return;
  int b = i / (R * C);
  int rc = i - b * (R * C);
  int r = rc / C;
  int c = rc - r * C;
  dst[(b * C + c) * R + r] = (bf16)src[i];   // [b][R][C] -> [b][C][R]
}

__global__ void prep_wf_k(const float* __restrict__ wf, bf16* __restrict__ dst) {
  int i = blockIdx.x * blockDim.x + threadIdx.x;  // 80*32
  if (i >= 80 * 32) return;
  int c = i >> 5, r = i & 31;
  dst[i] = (c < VOC) ? (bf16)wf[r * VOC + c] : (bf16)0.0f;  // [80 cols][32 k], cols 65..79 zero
}

// ---------------- fused transformer ----------------
// R8-proven math (swapped Q/K/PV/FFN1, packed stores). Barrier-free: all LDS
// wave-private, LDS_FENCE at stage edges. Biases folded into MFMA C-operand.
struct __align__(16) SeqLds {
  bf16 h[16][40];    // activations [token][dim 0..31], pad 32..39
  bf16 q[16][72];    // q rows / attn-out bounce [token][64], pad 64..71
  bf16 k[16][72];
  union {
    struct {
      bf16 vT[64][24];  // [vdim][tok 0..15], stride 48B
      bf16 p [16][24];  // [query][key 0..15], stride 48B
    } att;
    bf16 mbuf[16][72];  // FFN relu bounce [tok][hid], two 32-col parity windows
  } u;
};                      // 9728 B/seq, 38912 B/block

#define MFMA(a,b,c) __builtin_amdgcn_mfma_f32_16x16x32_bf16((a),(b),(c),0,0,0)

static __device__ __forceinline__ f32x4 splat4(float v) {
  f32x4 s; s[0] = v; s[1] = v; s[2] = v; s[3] = v; return s;
}

__global__ __launch_bounds__(128)
void xformer_k(const int* __restrict__ x, const float* __restrict__ emb, const float* __restrict__ pos,
               const float* __restrict__ bq, const float* __restrict__ bk, const float* __restrict__ bv,
               const float* __restrict__ bo, const float* __restrict__ ga, const float* __restrict__ ba,
               const float* __restrict__ b1, const float* __restrict__ b2,
               const float* __restrict__ gm, const float* __restrict__ bm,
               const float* __restrict__ bfin,
               const bf16* __restrict__ ws, float* __restrict__ out)
{
  __shared__ SeqLds sh[4];           // 4 seqs per block (2 waves x 2 seqs), wave-private
  const int tid  = threadIdx.x;
  const int wv   = tid >> 6;
  const int lane = tid & 63;
  const int lo   = lane & 15;        // MFMA A-row / B-col / D-col index
  const int hi   = lane >> 4;        // 0..3 (k-group / D-row group)
  const int seq0 = blockIdx.x * 4 + wv * 2;

  const bf16* wqT = ws + WS_WQ;      // [l*4+h][64 out][32 k]
  const bf16* wkT = ws + WS_WK;
  const bf16* wvT = ws + WS_WV;
  const bf16* woT = ws + WS_WO;      // [l][32 out][256 k]
  const bf16* w1T = ws + WS_W1;      // [l][2048 hid][32 k]
  const bf16* w2T = ws + WS_W2;      // [l][32 out][2048 k]
  const bf16* wfT = ws + WS_WF;      // [80 voc][32 k]

  const f32x4 fz = {0.f, 0.f, 0.f, 0.f};
  const bf16x8 bz8 = {(bf16)0.f,(bf16)0.f,(bf16)0.f,(bf16)0.f,
                      (bf16)0.f,(bf16)0.f,(bf16)0.f,(bf16)0.f};

  // ---- embedding: h = (emb[x] + pos) * sqrt(32) ----
  for (int si = 0; si < 2; ++si) {
    SeqLds& L = sh[wv*2+si];
    int s = seq0 + si;
    #pragma unroll
    for (int i = 0; i < 8; ++i) {
      int idx = i * 64 + lane;       // 0..511 over [16][32]
      int r = idx >> 5, c = idx & 31;
      int id = x[s * 16 + r];
      id = id < 0 ? 0 : (id >= VOC ? VOC - 1 : id);
      float v = (emb[id * 32 + c] + pos[r * 32 + c]) * 5.656854249492381f;
      L.h[r][c] = (bf16)v;
    }
  }
  LDS_FENCE();                       // emb writes -> stage A h reads

  for (int l = 0; l < 2; ++l) {
    // ================= attention =================
    // accO init = bo (bias-in-accumulator); D layout [tok=4hi+r][out=n2*16+lo]
    f32x4 accO[2][2];
    {
      float bo0 = bo[l*32 + lo], bo1 = bo[l*32 + 16 + lo];
      accO[0][0] = splat4(bo0); accO[0][1] = splat4(bo1);
      accO[1][0] = splat4(bo0); accO[1][1] = splat4(bo1);
    }
    for (int hh = 0; hh < 4; ++hh) {
      const int hb = (l*4 + hh) * 64;
      // ---- stage A: q,k,v projections; Q/K swapped (packed), V original (packed) ----
      #pragma unroll
      for (int nt = 0; nt < 4; ++nt) {
        int colh = nt * 16 + lo;                         // 0..63 within head
        int wofs = (hb + colh) * 32 + hi * 8;
        bf16x8 wq8 = *(const bf16x8*)(wqT + wofs);
        bf16x8 wk8 = *(const bf16x8*)(wkT + wofs);
        bf16x8 wv8 = *(const bf16x8*)(wvT + wofs);
        f32x4 bq4 = *(const f32x4*)(bq + hb + nt*16 + hi*4);
        f32x4 bk4 = *(const f32x4*)(bk + hb + nt*16 + hi*4);
        f32x4 bv4 = splat4(bv[hb + colh]);
        #pragma unroll
        for (int si = 0; si < 2; ++si) {
          SeqLds& L = sh[wv*2+si];
          bf16x8 a = *(const bf16x8*)(&L.h[lo][hi*8]);
          f32x4 dq = MFMA(wq8, a, bq4);  // swapped: Q[out=nt16+4hi+r][tok=lo], bias in C
          f32x4 dk = MFMA(wk8, a, bk4);
          f32x4 dv = MFMA(a, wv8, bv4);  // original: V[tok=4hi+r][vdim=colh], bias in C
          bf16x4 pq, pk, pv;
          #pragma unroll
          for (int r = 0; r < 4; ++r) {
            pq[r] = (bf16)dq[r];
            pk[r] = (bf16)dk[r];
            pv[r] = (bf16)dv[r];
          }
          *(bf16x4*)(&L.q[lo][nt*16 + hi*4])  = pq;   // q[tok][out]
          *(bf16x4*)(&L.k[lo][nt*16 + hi*4])  = pk;   // k[tok][out]
          *(bf16x4*)(&L.u.att.vT[colh][hi*4]) = pv;   // vT[vdim][tok]
        }
      }
      LDS_FENCE();                    // A writes -> B reads
      // ---- stage B: scores + softmax -> p ----
      #pragma unroll
      for (int si = 0; si < 2; ++si) {
        SeqLds& L = sh[wv*2+si];
        f32x4 sf = fz;
        #pragma unroll
        for (int kk = 0; kk < 2; ++kk) {
          bf16x8 aq  = *(const bf16x8*)(&L.q[lo][kk*32 + hi*8]);   // A row = query = lo
          bf16x8 bk8 = *(const bf16x8*)(&L.k[lo][kk*32 + hi*8]);   // B col = key = lo
          sf = MFMA(aq, bk8, sf);
        }
        // D: col=lo=key, row=hi*4+r=query
        #pragma unroll
        for (int r = 0; r < 4; ++r) {
          int row = hi*4 + r;
          float v0 = (lo <= row) ? sf[r] * 0.125f : -30000.0f;   // causal mask
          float mx = v0;
          mx = fmaxf(mx, __shfl_xor(mx, 1));
          mx = fmaxf(mx, __shfl_xor(mx, 2));
          mx = fmaxf(mx, __shfl_xor(mx, 4));
          mx = fmaxf(mx, __shfl_xor(mx, 8));
          float e = __expf(v0 - mx);
          float sm = e;
          sm += __shfl_xor(sm, 1);
          sm += __shfl_xor(sm, 2);
          sm += __shfl_xor(sm, 4);
          sm += __shfl_xor(sm, 8);
          L.u.att.p[row][lo] = (bf16)(e / sm);
        }
      }
      LDS_FENCE();                    // B writes -> C reads
      // ---- stage C: o = p @ v, swapped (packed store) ----
      #pragma unroll
      for (int si = 0; si < 2; ++si) {
        SeqLds& L = sh[wv*2+si];
        bf16x8 ap = (hi < 2) ? *(const bf16x8*)(&L.u.att.p[lo][hi*8]) : bz8;
        #pragma unroll
        for (int nt = 0; nt < 4; ++nt) {
          bf16x8 bv8 = (hi < 2) ? *(const bf16x8*)(&L.u.att.vT[nt*16+lo][hi*8]) : bz8;
          f32x4 o = MFMA(bv8, ap, fz);   // swapped: O[tok=lo][v=nt16+4hi+r]
          bf16x4 po;
          #pragma unroll
          for (int r = 0; r < 4; ++r) po[r] = (bf16)o[r];
          *(bf16x4*)(&L.q[lo][nt*16 + hi*4]) = po;    // q reused as o[tok][v]
        }
      }
      LDS_FENCE();                    // C writes -> D reads
      // ---- stage D: out-proj accumulate ----
      #pragma unroll
      for (int si = 0; si < 2; ++si) {
        SeqLds& L = sh[wv*2+si];
        #pragma unroll
        for (int kk = 0; kk < 2; ++kk) {
          bf16x8 ao = *(const bf16x8*)(&L.q[lo][kk*32 + hi*8]);
          #pragma unroll
          for (int n2 = 0; n2 < 2; ++n2) {
            bf16x8 bw = *(const bf16x8*)(woT + (l*32 + n2*16 + lo)*256 + hh*64 + kk*32 + hi*8);
            accO[si][n2] = MFMA(ao, bw, accO[si][n2]);
          }
        }
      }
      LDS_FENCE();                    // D reads -> next-head A writes (compiler order)
    }
    // ---- residual + LN(ga,ba) -> h (bo already in accO) ----
    #pragma unroll
    for (int si = 0; si < 2; ++si) {
      SeqLds& L = sh[wv*2+si];
      float g0 = ga[l*32 + lo], g1 = ga[l*32 + 16 + lo];
      float e0 = ba[l*32 + lo], e1 = ba[l*32 + 16 + lo];
      #pragma unroll
      for (int r = 0; r < 4; ++r) {
        int row = hi*4 + r;
        float v0 = accO[si][0][r] + (float)L.h[row][lo];
        float v1 = accO[si][1][r] + (float)L.h[row][16+lo];
        float s1 = v0 + v1, s2 = v0*v0 + v1*v1;
        s1 += __shfl_xor(s1, 1); s2 += __shfl_xor(s2, 1);
        s1 += __shfl_xor(s1, 2); s2 += __shfl_xor(s2, 2);
        s1 += __shfl_xor(s1, 4); s2 += __shfl_xor(s2, 4);
        s1 += __shfl_xor(s1, 8); s2 += __shfl_xor(s2, 8);
        float mean = s1 * (1.f/32.f);
        float var  = s2 * (1.f/32.f) - mean*mean;
        float rs   = rsqrtf(fabsf(var) + 1e-5f);
        L.h[row][lo]    = (bf16)((v0-mean)*rs*g0 + e0);
        L.h[row][16+lo] = (bf16)((v1-mean)*rs*g1 + e1);
      }
    }
    LDS_FENCE();                      // LN1 h-writes -> FFN ah reads
    // ================= FFN ================= (swapped GEMM1, packed stores, fences only)
    f32x4 acc2[2][2];
    {
      float b20 = b2[l*32 + lo], b21 = b2[l*32 + 16 + lo];
      acc2[0][0] = splat4(b20); acc2[0][1] = splat4(b21);
      acc2[1][0] = splat4(b20); acc2[1][1] = splat4(b21);
    }
    bf16x8 ah[2];
    #pragma unroll
    for (int si = 0; si < 2; ++si) ah[si] = *(const bf16x8*)(&sh[wv*2+si].h[lo][hi*8]);
    const bf16* w1l = w1T + l*65536;
    const bf16* w2l = w2T + l*65536;
    const float* b1l = b1 + l*2048;
    // preload kk=0 weights + biases
    bf16x8 w1c0 = *(const bf16x8*)(w1l + (lo)*32 + hi*8);
    bf16x8 w1c1 = *(const bf16x8*)(w1l + (16 + lo)*32 + hi*8);
    bf16x8 w2c0 = *(const bf16x8*)(w2l + (lo)*2048 + hi*8);
    bf16x8 w2c1 = *(const bf16x8*)(w2l + (16 + lo)*2048 + hi*8);
    f32x4  b1c0 = *(const f32x4*)(b1l + hi*4);
    f32x4  b1c1 = *(const f32x4*)(b1l + 16 + hi*4);
    for (int kk = 0; kk < 64; ++kk) {
      const int w = (kk & 1) * 32;    // parity window in mbuf
      // prefetch next-iteration weights + biases (stay in flight across fence)
      const int kn = (kk + 1) & 63;
      bf16x8 w1n0 = *(const bf16x8*)(w1l + (kn*32 + lo)*32 + hi*8);
      bf16x8 w1n1 = *(const bf16x8*)(w1l + (kn*32 + 16 + lo)*32 + hi*8);
      bf16x8 w2n0 = *(const bf16x8*)(w2l + (lo)*2048 + kn*32 + hi*8);
      bf16x8 w2n1 = *(const bf16x8*)(w2l + (16 + lo)*2048 + kn*32 + hi*8);
      f32x4  b1n0 = *(const f32x4*)(b1l + kn*32 + hi*4);
      f32x4  b1n1 = *(const f32x4*)(b1l + kn*32 + 16 + hi*4);
      // GEMM1 (swapped, bias in C) + relu, packed store into window w
      #pragma unroll
      for (int si = 0; si < 2; ++si) {
        SeqLds& L = sh[wv*2+si];
        f32x4 d0 = MFMA(w1c0, ah[si], b1c0);  // m[hid=kk32+4hi+r][tok=lo]
        f32x4 d1 = MFMA(w1c1, ah[si], b1c1);  // m[hid=kk32+16+4hi+r][tok=lo]
        bf16x4 m0, m1;
        #pragma unroll
        for (int r = 0; r < 4; ++r) {
          m0[r] = (bf16)fmaxf(d0[r], 0.f);
          m1[r] = (bf16)fmaxf(d1[r], 0.f);
        }
        *(bf16x4*)(&L.u.mbuf[lo][w + hi*4])      = m0;   // mbuf[tok][hid]
        *(bf16x4*)(&L.u.mbuf[lo][w + 16 + hi*4]) = m1;
      }
      LDS_FENCE();                    // m writes -> mf reads (same window)
      #pragma unroll
      for (int si = 0; si < 2; ++si) {
        bf16x8 am = *(const bf16x8*)(&sh[wv*2+si].u.mbuf[lo][w + hi*8]);
        acc2[si][0] = MFMA(am, w2c0, acc2[si][0]);
        acc2[si][1] = MFMA(am, w2c1, acc2[si][1]);
      }
      w1c0 = w1n0; w1c1 = w1n1; w2c0 = w2n0; w2c1 = w2n1; b1c0 = b1n0; b1c1 = b1n1;
    }
    LDS_FENCE();
    // ---- residual + LN(gm,bm) -> h (b2 already in acc2) ----
    #pragma unroll
    for (int si = 0; si < 2; ++si) {
      SeqLds& L = sh[wv*2+si];
      float g0 = gm[l*32 + lo], g1 = gm[l*32 + 16 + lo];
      float e0 = bm[l*32 + lo], e1 = bm[l*32 + 16 + lo];
      #pragma unroll
      for (int r = 0; r < 4; ++r) {
        int row = hi*4 + r;
        float v0 = acc2[si][0][r] + (float)L.h[row][lo];
        float v1 = acc2[si][1][r] + (float)L.h[row][16+lo];
        float s1 = v0 + v1, s2 = v0*v0 + v1*v1;
        s1 += __shfl_xor(s1, 1); s2 += __shfl_xor(s2, 1);
        s1 += __shfl_xor(s1, 2); s2 += __shfl_xor(s2, 2);
        s1 += __shfl_xor(s1, 4); s2 += __shfl_xor(s2, 4);
        s1 += __shfl_xor(s1, 8); s2 += __shfl_xor(s2, 8);
        float mean = s1 * (1.f/32.f);
        float var  = s2 * (1.f/32.f) - mean*mean;
        float rs   = rsqrtf(fabsf(var) + 1e-5f);
        L.h[row][lo]    = (bf16)((v0-mean)*rs*g0 + e0);
        L.h[row][16+lo] = (bf16)((v1-mean)*rs*g1 + e1);
      }
    }
    LDS_FENCE();                      // LN2 h-writes -> next-layer/classifier reads
  }

  // ---- final classifier: h @ Wf + bf (bias in C) -> out [s,16,65] (f32) ----
  #pragma unroll
  for (int si = 0; si < 2; ++si) {
    SeqLds& L = sh[wv*2+si];
    int s = seq0 + si;
    bf16x8 a = *(const bf16x8*)(&L.h[lo][hi*8]);
    #pragma unroll
    for (int nt = 0; nt < 5; ++nt) {
      int col = nt*16 + lo;
      f32x4 cb = splat4((col < VOC) ? bfin[col] : 0.f);
      bf16x8 w = *(const bf16x8*)(wfT + (nt*16+lo)*32 + hi*8);
      f32x4 d = MFMA(a, w, cb);
      if (col < VOC) {
        #pragma unroll
        for (int r = 0; r < 4; ++r)
          out[(s*16 + hi*4 + r)*VOC + col] = d[r];
      }
    }
  }
}

extern "C" void kernel_launch(void* const* d_in, const int* in_sizes, int n_in,
                              void* d_out, int out_size, void* d_ws, size_t ws_size,
                              hipStream_t stream) {
  const int*   x   = (const int*)d_in[0];
  const float* emb = (const float*)d_in[1];
  const float* pos = (const float*)d_in[2];
  const float* Wq  = (const float*)d_in[3];
  const float* bq  = (const float*)d_in[4];
  const float* Wk  = (const float*)d_in[5];
  const float* bk  = (const float*)d_in[6];
  const float* Wv  = (const float*)d_in[7];
  const float* bv  = (const float*)d_in[8];
  const float* Wo  = (const float*)d_in[9];
  const float* bo  = (const float*)d_in[10];
  const float* ga  = (const float*)d_in[11];
  const float* ba  = (const float*)d_in[12];
  const float* W1  = (const float*)d_in[13];
  const float* b1  = (const float*)d_in[14];
  const float* W2  = (const float*)d_in[15];
  const float* b2  = (const float*)d_in[16];
  const float* gm  = (const float*)d_in[17];
  const float* bm  = (const float*)d_in[18];
  const float* Wf  = (const float*)d_in[19];
  const float* bfin= (const float*)d_in[20];

  bf16* ws = (bf16*)d_ws;

  // transpose weights (f32 -> bf16) into MFMA [out][k] layout (k contiguous)
  transpose_f32bf16_k<<<64, 256, 0, stream>>>(Wq, ws + WS_WQ, 8, 32, 64);
  transpose_f32bf16_k<<<64, 256, 0, stream>>>(Wk, ws + WS_WK, 8, 32, 64);
  transpose_f32bf16_k<<<64, 256, 0, stream>>>(Wv, ws + WS_WV, 8, 32, 64);
  transpose_f32bf16_k<<<64, 256, 0, stream>>>(Wo, ws + WS_WO, 2, 256, 32);
  transpose_f32bf16_k<<<512, 256, 0, stream>>>(W1, ws + WS_W1, 2, 32, 2048);
  transpose_f32bf16_k<<<512, 256, 0, stream>>>(W2, ws + WS_W2, 2, 2048, 32);
  prep_wf_k<<<10, 256, 0, stream>>>(Wf, ws + WS_WF);

  // fused transformer: 1024 blocks x 128 threads (2 waves x 2 seqs), barrier-free
  xformer_k<<<1024, 128, 0, stream>>>(x, emb, pos, bq, bk, bv, bo, ga, ba,
                                      b1, b2, gm, bm, bfin,
                                      ws, (float*)d_out);
}